// Round 1
// baseline (8120.816 us; speedup 1.0000x reference)
//
#include <hip/hip_runtime.h>
#include <math.h>

typedef float vf4 __attribute__((ext_vector_type(4)));

#define SEQ   2048
#define DM    1024
#define NH    16
#define DKH   64
// log2(10000)
#define LOG2_THETA 13.287712379549449f

// ---------------------------------------------------------------------------
// Projection GEMM: C[m,n] = sum_k A[m,k] * W[n,k]   (A row-major MxK, W row-major NxK)
// 128x128 tile, BK=32, 256 threads, 8x8 per thread.
// Interleaved ownership: rows r = tr + 16*i, cols c = tc + 16*j  -> pad 36 makes
// all ds_read_b128 broadcast or 2-way (free). RoPE fused in epilogue via shfl_xor(1).
// ---------------------------------------------------------------------------
__global__ __launch_bounds__(256, 2) void proj_kernel(
    const float* __restrict__ A,
    const float* __restrict__ W0, const float* __restrict__ W1, const float* __restrict__ W2,
    float* __restrict__ C0, float* __restrict__ C1, float* __restrict__ C2,
    const int* __restrict__ tokpos,
    int M, int N, int K, int ropeMask)
{
    const int z = blockIdx.z;
    const float* __restrict__ W = (z == 0) ? W0 : ((z == 1) ? W1 : W2);
    float* __restrict__ C       = (z == 0) ? C0 : ((z == 1) ? C1 : C2);
    const bool do_rope = (ropeMask >> z) & 1;

    __shared__ float As[128][36];   // 144B row stride: reads are broadcast / 2-way
    __shared__ float Ws[128][36];

    const int t  = threadIdx.x;
    const int tr = t >> 4;          // 0..15
    const int tc = t & 15;          // 0..15
    const int brow = blockIdx.x * 128;
    const int bcol = blockIdx.y * 128;

    // staging: 128x32 tile = 1024 float4, 4 per thread
    const int lrow = t >> 3;        // 0..31
    const int lc4  = (t & 7) << 2;  // 0..28

    float acc[8][8];
    #pragma unroll
    for (int i = 0; i < 8; ++i)
        #pragma unroll
        for (int j = 0; j < 8; ++j) acc[i][j] = 0.f;

    for (int k0 = 0; k0 < K; k0 += 32) {
        __syncthreads();
        #pragma unroll
        for (int i = 0; i < 4; ++i) {
            const int row = lrow + 32 * i;
            *(vf4*)(&As[row][lc4]) = *(const vf4*)(A + (size_t)(brow + row) * K + k0 + lc4);
            *(vf4*)(&Ws[row][lc4]) = *(const vf4*)(W + (size_t)(bcol + row) * K + k0 + lc4);
        }
        __syncthreads();
        #pragma unroll
        for (int kk = 0; kk < 32; kk += 4) {
            vf4 a[8], b[8];
            #pragma unroll
            for (int i = 0; i < 8; ++i) a[i] = *(const vf4*)(&As[tr + 16 * i][kk]);
            #pragma unroll
            for (int j = 0; j < 8; ++j) b[j] = *(const vf4*)(&Ws[tc + 16 * j][kk]);
            #pragma unroll
            for (int i = 0; i < 8; ++i)
                #pragma unroll
                for (int j = 0; j < 8; ++j)
                    acc[i][j] += a[i].x * b[j].x + a[i].y * b[j].y
                               + a[i].z * b[j].z + a[i].w * b[j].w;
        }
    }

    if (do_rope) {
        // col = bcol + tc + 16j ; head-local pair index f = ((col & 63) >> 1)
        // even col: r1 = x1*cos - x2*sin ; odd col: r2 = x1*sin + x2*cos
        // pair partner lives in lane^1 (same rows, same j).
        float pos[8];
        #pragma unroll
        for (int i = 0; i < 8; ++i)
            pos[i] = (float)tokpos[(brow + tr + 16 * i) & (SEQ - 1)];
        #pragma unroll
        for (int j = 0; j < 8; ++j) {
            const int   col = tc + 16 * j;                  // bcol is a multiple of 64
            const float f   = (float)((col & 63) >> 1);
            const float inv = exp2f(f * (-LOG2_THETA / 32.0f));  // theta^(-2f/64)
            #pragma unroll
            for (int i = 0; i < 8; ++i) {
                float sv, cv;
                sincosf(pos[i] * inv, &sv, &cv);
                const float self  = acc[i][j];
                const float other = __shfl_xor(self, 1);
                acc[i][j] = (tc & 1) ? fmaf(other, sv, self * cv)    // odd:  x1*sin + x2*cos
                                     : fmaf(-other, sv, self * cv);  // even: x1*cos - x2*sin
            }
        }
    }

    #pragma unroll
    for (int i = 0; i < 8; ++i) {
        float* crow = C + (size_t)(brow + tr + 16 * i) * N + bcol;
        #pragma unroll
        for (int j = 0; j < 8; ++j)
            crow[tc + 16 * j] = acc[i][j];
    }
}

// ---------------------------------------------------------------------------
// Causal flash attention, fp32. One block per (b,h,q-tile of 64 rows).
// 256 threads as 16x16; scores: rows tr+16i, cols tc+16j (interleaved, conflict-free);
// O accum: rows tr+16i, dims 4*tc+j (contiguous -> float4 stores).
// Ks buffer is reused to hold P for the PV stage (keeps static LDS at 52KB).
// ---------------------------------------------------------------------------
__global__ __launch_bounds__(256, 2) void attn_kernel(
    const float* __restrict__ q, const float* __restrict__ k,
    const float* __restrict__ v, float* __restrict__ o)
{
    __shared__ float Qs[64][68];
    __shared__ float Ks[64][68];   // scores' K operand, then P
    __shared__ float Vs[64][68];

    const int bh = blockIdx.y;
    const int b  = bh >> 4;          // / NH
    const int h  = bh & (NH - 1);
    const int qi = (int)gridDim.x - 1 - (int)blockIdx.x;   // heavy tiles dispatch first

    const int t  = threadIdx.x;
    const int tr = t >> 4;
    const int tc = t & 15;

    const size_t base = (size_t)b * SEQ * DM + (size_t)h * DKH;

    // staging: 64 rows x 16 float4 per row, 4 float4 per thread, fully coalesced
    const int lrow = t >> 4;
    const int lc4  = (t & 15) << 2;

    #pragma unroll
    for (int i = 0; i < 4; ++i) {
        const int row = lrow + 16 * i;
        vf4 qv = *(const vf4*)(q + base + (size_t)(qi * 64 + row) * DM + lc4);
        *(vf4*)(&Qs[row][lc4]) = qv * 0.125f;   // 1/sqrt(64) folded into Q
    }

    float oacc[4][4];
    float m_run[4], l_run[4];
    #pragma unroll
    for (int i = 0; i < 4; ++i) {
        m_run[i] = -INFINITY; l_run[i] = 0.f;
        #pragma unroll
        for (int j = 0; j < 4; ++j) oacc[i][j] = 0.f;
    }

    for (int kt = 0; kt <= qi; ++kt) {
        __syncthreads();                       // prev iter done with Ks(P)/Vs
        #pragma unroll
        for (int i = 0; i < 4; ++i) {
            const int row = lrow + 16 * i;
            *(vf4*)(&Ks[row][lc4]) = *(const vf4*)(k + base + (size_t)(kt * 64 + row) * DM + lc4);
            *(vf4*)(&Vs[row][lc4]) = *(const vf4*)(v + base + (size_t)(kt * 64 + row) * DM + lc4);
        }
        __syncthreads();

        // ---- S = (Q/8) K^T ----
        float sacc[4][4];
        #pragma unroll
        for (int i = 0; i < 4; ++i)
            #pragma unroll
            for (int j = 0; j < 4; ++j) sacc[i][j] = 0.f;

        #pragma unroll
        for (int kk = 0; kk < 64; kk += 4) {
            vf4 a[4], bb[4];
            #pragma unroll
            for (int i = 0; i < 4; ++i) a[i]  = *(const vf4*)(&Qs[tr + 16 * i][kk]);
            #pragma unroll
            for (int j = 0; j < 4; ++j) bb[j] = *(const vf4*)(&Ks[tc + 16 * j][kk]);
            #pragma unroll
            for (int i = 0; i < 4; ++i)
                #pragma unroll
                for (int j = 0; j < 4; ++j)
                    sacc[i][j] += a[i].x * bb[j].x + a[i].y * bb[j].y
                                + a[i].z * bb[j].z + a[i].w * bb[j].w;
        }

        if (kt == qi) {        // diagonal tile: causal mask (local compare is exact)
            #pragma unroll
            for (int i = 0; i < 4; ++i)
                #pragma unroll
                for (int j = 0; j < 4; ++j)
                    if (tc + 16 * j > tr + 16 * i) sacc[i][j] = -INFINITY;
        }

        // ---- online softmax (row lives in 16 consecutive lanes) ----
        #pragma unroll
        for (int i = 0; i < 4; ++i) {
            float mx = fmaxf(fmaxf(sacc[i][0], sacc[i][1]), fmaxf(sacc[i][2], sacc[i][3]));
            mx = fmaxf(mx, __shfl_xor(mx, 1));
            mx = fmaxf(mx, __shfl_xor(mx, 2));
            mx = fmaxf(mx, __shfl_xor(mx, 4));
            mx = fmaxf(mx, __shfl_xor(mx, 8));
            const float mn   = fmaxf(m_run[i], mx);      // finite from first tile on
            const float corr = __expf(m_run[i] - mn);    // exp(-inf)=0 on first tile
            m_run[i] = mn;
            float rs = 0.f;
            #pragma unroll
            for (int j = 0; j < 4; ++j) {
                sacc[i][j] = __expf(sacc[i][j] - mn);    // masked -> 0
                rs += sacc[i][j];
            }
            rs += __shfl_xor(rs, 1);
            rs += __shfl_xor(rs, 2);
            rs += __shfl_xor(rs, 4);
            rs += __shfl_xor(rs, 8);
            l_run[i] = l_run[i] * corr + rs;
            #pragma unroll
            for (int j = 0; j < 4; ++j) oacc[i][j] *= corr;
        }

        __syncthreads();                       // everyone done reading Ks as K
        #pragma unroll
        for (int i = 0; i < 4; ++i)
            #pragma unroll
            for (int j = 0; j < 4; ++j)
                Ks[tr + 16 * i][tc + 16 * j] = sacc[i][j];   // P -> Ks buffer
        __syncthreads();                       // P visible

        // ---- O += P V ----
        #pragma unroll
        for (int cc = 0; cc < 64; cc += 4) {
            vf4 p4[4], v4[4];
            #pragma unroll
            for (int i = 0; i < 4; ++i) p4[i] = *(const vf4*)(&Ks[tr + 16 * i][cc]);
            #pragma unroll
            for (int l = 0; l < 4; ++l) v4[l] = *(const vf4*)(&Vs[cc + l][tc << 2]);
            #pragma unroll
            for (int i = 0; i < 4; ++i)
                #pragma unroll
                for (int j = 0; j < 4; ++j)
                    oacc[i][j] += p4[i][0] * v4[0][j] + p4[i][1] * v4[1][j]
                                + p4[i][2] * v4[2][j] + p4[i][3] * v4[3][j];
        }
    }

    #pragma unroll
    for (int i = 0; i < 4; ++i) {
        const float invl = 1.0f / l_run[i];
        vf4 ov;
        ov.x = oacc[i][0] * invl; ov.y = oacc[i][1] * invl;
        ov.z = oacc[i][2] * invl; ov.w = oacc[i][3] * invl;
        *(vf4*)(o + base + (size_t)(qi * 64 + tr + 16 * i) * DM + (tc << 2)) = ov;
    }
}

// ---------------------------------------------------------------------------
extern "C" void kernel_launch(void* const* d_in, const int* in_sizes, int n_in,
                              void* d_out, int out_size, void* d_ws, size_t ws_size,
                              hipStream_t stream)
{
    const float* x  = (const float*)d_in[0];
    const int*   tp = (const int*)d_in[1];
    const float* Wq = (const float*)d_in[2];
    const float* Wk = (const float*)d_in[3];
    const float* Wv = (const float*)d_in[4];
    const float* Wo = (const float*)d_in[5];
    float* out = (float*)d_out;

    const size_t NELEM = (size_t)2 * SEQ * DM;   // 4,194,304 floats = 16 MB
    float* qb = (float*)d_ws;                    // ws usage: 64 MB total
    float* kb = qb + NELEM;
    float* vb = kb + NELEM;
    float* ob = vb + NELEM;

    const int M = 2 * SEQ;                       // 4096 rows

    // fused Q/K/V projections (z selects W and destination), RoPE on z=0,1
    proj_kernel<<<dim3(M / 128, DM / 128, 3), dim3(256), 0, stream>>>(
        x, Wq, Wk, Wv, qb, kb, vb, tp, M, DM, DM, 0x3);

    // causal flash attention; output lands directly in (B,S,D) layout
    attn_kernel<<<dim3(SEQ / 64, 2 * NH), dim3(256), 0, stream>>>(qb, kb, vb, ob);

    // output projection
    proj_kernel<<<dim3(M / 128, DM / 128, 1), dim3(256), 0, stream>>>(
        ob, Wo, Wo, Wo, out, out, out, tp, M, DM, DM, 0x0);
}